// Round 15
// baseline (46.662 us; speedup 1.0000x reference)
//
#include <hip/hip_runtime.h>
#include <hip/hip_bf16.h>
#include <stdint.h>

#define B_  256
#define T_  1024
#define F_  16
#define N_  1024

typedef short bf16x8 __attribute__((ext_vector_type(8)));
typedef float f32x4  __attribute__((ext_vector_type(4)));

static __device__ __forceinline__ unsigned short f2bf(float x) {
  unsigned u = __builtin_bit_cast(unsigned, x);
  u += 0x7fffu + ((u >> 16) & 1u);
  return (unsigned short)(u >> 16);
}
static __device__ __forceinline__ float bf2f(unsigned short h) {
  unsigned u = ((unsigned)h) << 16;
  return __builtin_bit_cast(float, u);
}

// ---- pass 1: x[b][t][f] fp32 -> At2 fragment layout bf16 ----
// At2 element (f,b,k) at ((f*32+kc)*16+rb)*512 + lane*8 + j, where
// kc=k>>5, rb=b>>4, lane=((k>>3)&3)*16 + (b&15), j=k&7.
__global__ __launch_bounds__(256) void prep2_kernel(const float* __restrict__ x,
                                                    unsigned short* __restrict__ At2) {
  __shared__ unsigned short ld[16 * 1028];   // [b_local][t_local*16+f], pitch 1028
  const int rb = blockIdx.x >> 4, tc = blockIdx.x & 15;
  const int tid = threadIdx.x;
  const int tl = tid >> 2;            // t-local 0..63
  const int f4 = (tid & 3) * 4;       // f quad
#pragma unroll
  for (int i = 0; i < 16; ++i) {
    const float* src = x + (((size_t)(rb * 16 + i) * T_) + tc * 64 + tl) * F_ + f4;
    float4 v = *(const float4*)src;
    uint2 pk;
    pk.x = (unsigned)f2bf(v.x) | ((unsigned)f2bf(v.y) << 16);
    pk.y = (unsigned)f2bf(v.z) | ((unsigned)f2bf(v.w) << 16);
    *(uint2*)&ld[i * 1028 + tl * 16 + f4] = pk;
  }
  __syncthreads();
  const int w = tid >> 6, l = tid & 63;
#pragma unroll
  for (int it = 0; it < 8; ++it) {
    const int c = it * 4 + w;          // 0..31 = (f, kcl)
    const int f = c >> 1, kcl = c & 1;
    unsigned short t16[8];
#pragma unroll
    for (int j = 0; j < 8; ++j)
      t16[j] = ld[(l & 15) * 1028 + (kcl * 32 + ((l >> 4) * 8) + j) * 16 + f];
    uint4 q;
    q.x = (unsigned)t16[0] | ((unsigned)t16[1] << 16);
    q.y = (unsigned)t16[2] | ((unsigned)t16[3] << 16);
    q.z = (unsigned)t16[4] | ((unsigned)t16[5] << 16);
    q.w = (unsigned)t16[6] | ((unsigned)t16[7] << 16);
    *(uint4*)(At2 + (((size_t)(f * 32 + tc * 2 + kcl) * 16 + rb) << 9) + l * 8) = q;
  }
}

// ---- pass 2 (K-SPLIT): one K-half per block; bf16 partial out ----
// Grid 512 = 16f x 16nt x 2kh. Per block: wave w streams rows
// t0 = kh*512 + w*32 (recurrence in regs, boundary re-read), packs V B-frags
// to vT (64 KB); ONE barrier; 16 barrier-free K-steps. Partial (no bias):
// part[((kh*16+f)*B + brow)*N + n] bf16. 2 blocks/CU -> their memory phases
// mutually overlap; serial chain per block is halved vs full-K.
__global__ __launch_bounds__(1024, 8) void gemm_split_kernel(const unsigned short* __restrict__ At2,
                                                             const float* __restrict__ TW,
                                                             const float* __restrict__ RW,
                                                             unsigned short* __restrict__ part) {
  __shared__ unsigned short vT[16 * 4 * 64 * 8];   // 64 KB

  const int tid = threadIdx.x;
  // XCD chunk swizzle: 512 blocks -> 64 consecutive bids per XCD (2 f-panels).
  // bids 2j/2j+1 share (f, ntile), differ in kh.
  const int bid = (blockIdx.x & 7) * 64 + (blockIdx.x >> 3);
  const int f   = bid >> 5;
  const int n0  = ((bid >> 1) & 15) * 64;
  const int kh  = bid & 1;
  const int w = tid >> 6, l = tid & 63;     // wave 0..15, lane 0..63
  const int lrow = l & 15, lg = l >> 4;

  const float* TWf = TW + (size_t)f * (T_ * N_) + n0;
  const float* RWf = RW + (size_t)f * (T_ * N_) + n0;
  const unsigned short* Af2 = At2 + ((size_t)f * 32 * 16 * 512);

  f32x4 acc[4];
#pragma unroll
  for (int nt = 0; nt < 4; ++nt)
    acc[nt] = (f32x4){0.f, 0.f, 0.f, 0.f};

  const int t0 = kh * 512 + w * 32;
  float ptw = 0.f, prw = 0.f;
  if (t0 > 0) {
    ptw = TWf[(size_t)(t0 - 1) * N_ + l];
    prw = RWf[(size_t)(t0 - 1) * N_ + l];
  }
  float twv[32], rwv[32];
#pragma unroll
  for (int i = 0; i < 32; ++i) {
    twv[i] = TWf[(size_t)(t0 + i) * N_ + l];
    rwv[i] = RWf[(size_t)(t0 + i) * N_ + l];
  }
  // per-lane column recurrence + packed B-frag writes
#pragma unroll
  for (int b = 0; b < 4; ++b) {
    unsigned pk[4];
    unsigned lo32 = 0;
#pragma unroll
    for (int i = 0; i < 8; ++i) {
      const int tl = b * 8 + i;
      const int tg = t0 + tl;
      const float tw = twv[tl], rw = rwv[tl];
      const float c1 = (tg < T_ - 1) ? 0.5f : 1.0f;
      const float c2 = (tg < T_ - 1) ? 0.5f : 0.0f;
      const float pterm = (tg >= 1) ? 0.5f * (ptw - prw) : 0.0f;
      const unsigned short us = f2bf(c1 * tw + c2 * rw + pterm);
      if ((i & 1) == 0) lo32 = us; else pk[i >> 1] = lo32 | ((unsigned)us << 16);
      ptw = tw; prw = rw;
    }
    uint4 q; q.x = pk[0]; q.y = pk[1]; q.z = pk[2]; q.w = pk[3];
    *(uint4*)&vT[((w * 4 + (l >> 4)) * 64 + b * 16 + (l & 15)) * 8] = q;
  }
  __syncthreads();   // vT ready (only barrier in kernel)
  // ---- barrier-free K-half loop ----
#pragma unroll
  for (int kcl = 0; kcl < 16; ++kcl) {
    const int kc = kh * 16 + kcl;
    bf16x8 a = *(const bf16x8*)(Af2 + (((size_t)(kc * 16 + w)) << 9) + l * 8);
#pragma unroll
    for (int nt = 0; nt < 4; ++nt) {
      bf16x8 bfrag = *(const bf16x8*)&vT[((kcl * 4 + nt) * 64 + l) * 8];
      acc[nt] = __builtin_amdgcn_mfma_f32_16x16x32_bf16(a, bfrag, acc[nt], 0, 0, 0);
    }
  }
  // ---- store bf16 partial (coalesced 32B segments) ----
#pragma unroll
  for (int nt = 0; nt < 4; ++nt) {
    const int n = n0 + nt * 16 + lrow;
#pragma unroll
    for (int j = 0; j < 4; ++j) {
      const int brow = w * 16 + lg * 4 + j;
      part[((size_t)(kh * 16 + f) * B_ + brow) * N_ + n] = f2bf(acc[nt][j]);
    }
  }
}

// ---- pass 3 (K-SPLIT): part halves -> sum + bias -> out[B][N][F] fp32 ----
__global__ __launch_bounds__(256) void untile2_kernel(const unsigned short* __restrict__ part,
                                                      const float* __restrict__ tb,
                                                      const float* __restrict__ rb,
                                                      float* __restrict__ out) {
  __shared__ float ldF[16 * 1048];   // [f][n] fp32, padded pitch (67 KB)
  const int b = blockIdx.x, tid = threadIdx.x;
  const unsigned short* p0 = part;                        // kh=0
  const unsigned short* p1 = part + (size_t)F_ * B_ * N_; // kh=1
#pragma unroll
  for (int it = 0; it < 8; ++it) {
    const int idx = it * 256 + tid;
    const int f = idx >> 7, c = idx & 127;
    uint4 v0 = *(const uint4*)(p0 + ((size_t)f * B_ + b) * N_ + c * 8);
    uint4 v1 = *(const uint4*)(p1 + ((size_t)f * B_ + b) * N_ + c * 8);
    const unsigned short* a0 = (const unsigned short*)&v0;
    const unsigned short* a1 = (const unsigned short*)&v1;
#pragma unroll
    for (int j = 0; j < 8; ++j)
      ldF[f * 1048 + c * 8 + j] = bf2f(a0[j]) + bf2f(a1[j]);
  }
  __syncthreads();
  float* ob = out + (size_t)b * (N_ * F_);
#pragma unroll
  for (int it = 0; it < 16; ++it) {
    const int g = it * 256 + tid;
    const int n = g >> 2, f0 = (g & 3) * 4;
    float4 o;
    o.x = ldF[(f0 + 0) * 1048 + n] + tb[(f0 + 0) * N_ + n] + rb[(f0 + 0) * N_ + n];
    o.y = ldF[(f0 + 1) * 1048 + n] + tb[(f0 + 1) * N_ + n] + rb[(f0 + 1) * N_ + n];
    o.z = ldF[(f0 + 2) * 1048 + n] + tb[(f0 + 2) * N_ + n] + rb[(f0 + 2) * N_ + n];
    o.w = ldF[(f0 + 3) * 1048 + n] + tb[(f0 + 3) * N_ + n] + rb[(f0 + 3) * N_ + n];
    *(float4*)(ob + n * F_ + f0) = o;
  }
}

// ---- fallback: R14 full-K gemm (two-phase) + untile ----
template <int TMPOUT>
__global__ __launch_bounds__(1024, 4) void gemm_kernel(const unsigned short* __restrict__ At2,
                                                       const float* __restrict__ TW,
                                                       const float* __restrict__ RW,
                                                       const float* __restrict__ tb,
                                                       const float* __restrict__ rb,
                                                       float* __restrict__ out,
                                                       unsigned short* __restrict__ tmp) {
  __shared__ unsigned short vT[16 * 4 * 64 * 8];
  const int tid = threadIdx.x;
  const int bid = (blockIdx.x & 7) * 32 + (blockIdx.x >> 3);
  const int f  = bid >> 4;
  const int n0 = (bid & 15) * 64;
  const int w = tid >> 6, l = tid & 63;
  const int lrow = l & 15, lg = l >> 4;
  const float* TWf = TW + (size_t)f * (T_ * N_) + n0;
  const float* RWf = RW + (size_t)f * (T_ * N_) + n0;
  const unsigned short* Af2 = At2 + ((size_t)f * 32 * 16 * 512);
  f32x4 acc[4];
#pragma unroll
  for (int nt = 0; nt < 4; ++nt)
    acc[nt] = (f32x4){0.f, 0.f, 0.f, 0.f};
#pragma unroll
  for (int p = 0; p < 2; ++p) {
    const int t0 = p * 512 + w * 32;
    float twv[32], rwv[32];
    float ptw = 0.f, prw = 0.f;
    if (t0 > 0) {
      ptw = TWf[(size_t)(t0 - 1) * N_ + l];
      prw = RWf[(size_t)(t0 - 1) * N_ + l];
    }
#pragma unroll
    for (int i = 0; i < 32; ++i) {
      twv[i] = TWf[(size_t)(t0 + i) * N_ + l];
      rwv[i] = RWf[(size_t)(t0 + i) * N_ + l];
    }
    __syncthreads();
#pragma unroll
    for (int b = 0; b < 4; ++b) {
      unsigned pk[4];
      unsigned lo32 = 0;
#pragma unroll
      for (int i = 0; i < 8; ++i) {
        const int tl = b * 8 + i;
        const int tg = t0 + tl;
        const float tw = twv[tl], rw = rwv[tl];
        const float c1 = (tg < T_ - 1) ? 0.5f : 1.0f;
        const float c2 = (tg < T_ - 1) ? 0.5f : 0.0f;
        const float pterm = (tg >= 1) ? 0.5f * (ptw - prw) : 0.0f;
        const unsigned short us = f2bf(c1 * tw + c2 * rw + pterm);
        if ((i & 1) == 0) lo32 = us; else pk[i >> 1] = lo32 | ((unsigned)us << 16);
        ptw = tw; prw = rw;
      }
      uint4 q; q.x = pk[0]; q.y = pk[1]; q.z = pk[2]; q.w = pk[3];
      *(uint4*)&vT[((w * 4 + (l >> 4)) * 64 + b * 16 + (l & 15)) * 8] = q;
    }
    __syncthreads();
#pragma unroll
    for (int kcl = 0; kcl < 16; ++kcl) {
      const int kc = p * 16 + kcl;
      bf16x8 a = *(const bf16x8*)(Af2 + (((size_t)(kc * 16 + w)) << 9) + l * 8);
#pragma unroll
      for (int nt = 0; nt < 4; ++nt) {
        bf16x8 bfrag = *(const bf16x8*)&vT[((kcl * 4 + nt) * 64 + l) * 8];
        acc[nt] = __builtin_amdgcn_mfma_f32_16x16x32_bf16(a, bfrag, acc[nt], 0, 0, 0);
      }
    }
  }
#pragma unroll
  for (int nt = 0; nt < 4; ++nt) {
    const int n = n0 + nt * 16 + lrow;
    const float bsum = tb[f * N_ + n] + rb[f * N_ + n];
#pragma unroll
    for (int j = 0; j < 4; ++j) {
      const int brow = w * 16 + lg * 4 + j;
      const float v = acc[nt][j] + bsum;
      if (TMPOUT) {
        tmp[((size_t)f * B_ + brow) * N_ + n] = f2bf(v);
      } else {
        out[((size_t)brow * N_ + n) * F_ + f] = v;
      }
    }
  }
}

__global__ __launch_bounds__(256) void untile_kernel(const unsigned short* __restrict__ tmp,
                                                     float* __restrict__ out) {
  __shared__ unsigned short ld[16 * 1048];
  const int b = blockIdx.x, tid = threadIdx.x;
#pragma unroll
  for (int it = 0; it < 8; ++it) {
    const int idx = it * 256 + tid;
    const int f = idx >> 7, c = idx & 127;
    uint4 v = *(const uint4*)(tmp + ((size_t)f * B_ + b) * N_ + c * 8);
    *(uint4*)&ld[f * 1048 + c * 8] = v;
  }
  __syncthreads();
  float* ob = out + (size_t)b * (N_ * F_);
#pragma unroll
  for (int it = 0; it < 16; ++it) {
    const int g = it * 256 + tid;
    const int n = g >> 2, f0 = (g & 3) * 4;
    float4 o;
    o.x = bf2f(ld[(f0 + 0) * 1048 + n]);
    o.y = bf2f(ld[(f0 + 1) * 1048 + n]);
    o.z = bf2f(ld[(f0 + 2) * 1048 + n]);
    o.w = bf2f(ld[(f0 + 3) * 1048 + n]);
    *(float4*)(ob + n * F_ + f0) = o;
  }
}

extern "C" void kernel_launch(void* const* d_in, const int* in_sizes, int n_in,
                              void* d_out, int out_size, void* d_ws, size_t ws_size,
                              hipStream_t stream) {
  const float* x  = (const float*)d_in[0];
  const float* TW = (const float*)d_in[8];
  const float* tb = (const float*)d_in[9];
  const float* RW = (const float*)d_in[10];
  const float* rb = (const float*)d_in[11];
  float* out = (float*)d_out;

  unsigned short* At2 = (unsigned short*)d_ws;                      // 8 MB
  const size_t atBytes   = (size_t)F_ * B_ * T_ * sizeof(unsigned short);
  const size_t partBytes = (size_t)2 * F_ * B_ * N_ * sizeof(unsigned short);  // 16 MB
  const size_t tmpBytes  = (size_t)F_ * B_ * N_ * sizeof(unsigned short);      // 8 MB

  prep2_kernel<<<256, 256, 0, stream>>>(x, At2);
  if (ws_size >= atBytes + partBytes) {
    unsigned short* part = (unsigned short*)((char*)d_ws + atBytes);
    gemm_split_kernel<<<512, 1024, 0, stream>>>(At2, TW, RW, part);
    untile2_kernel<<<256, 256, 0, stream>>>(part, tb, rb, out);
  } else if (ws_size >= atBytes + tmpBytes) {
    unsigned short* tmp = (unsigned short*)((char*)d_ws + atBytes);
    gemm_kernel<1><<<256, 1024, 0, stream>>>(At2, TW, RW, tb, rb, out, tmp);
    untile_kernel<<<256, 256, 0, stream>>>(tmp, out);
  } else {
    gemm_kernel<0><<<256, 1024, 0, stream>>>(At2, TW, RW, tb, rb, out, nullptr);
  }
}

// Round 16
// 44.428 us; speedup vs baseline: 1.0503x; 1.0503x over previous
//
#include <hip/hip_runtime.h>
#include <hip/hip_bf16.h>
#include <stdint.h>

#define B_  256
#define T_  1024
#define F_  16
#define N_  1024

typedef short bf16x8 __attribute__((ext_vector_type(8)));
typedef float f32x4  __attribute__((ext_vector_type(4)));

static __device__ __forceinline__ unsigned short f2bf(float x) {
  unsigned u = __builtin_bit_cast(unsigned, x);
  u += 0x7fffu + ((u >> 16) & 1u);
  return (unsigned short)(u >> 16);
}
static __device__ __forceinline__ float bf2f(unsigned short h) {
  unsigned u = ((unsigned)h) << 16;
  return __builtin_bit_cast(float, u);
}
// async global->LDS DMA, 16B/lane; LDS dest = wave-uniform base + lane*16
static __device__ __forceinline__ void gload16(const void* g, void* l) {
  __builtin_amdgcn_global_load_lds((const __attribute__((address_space(1))) void*)g,
                                   (__attribute__((address_space(3))) void*)l, 16, 0, 0);
}

// ---- pass 1: x[b][t][f] fp32 -> At2 fragment layout bf16 ----
// At2 element (f,b,k) at ((f*32+kc)*16+rb)*512 + lane*8 + j, where
// kc=k>>5, rb=b>>4, lane=((k>>3)&3)*16 + (b&15), j=k&7.
__global__ __launch_bounds__(256) void prep2_kernel(const float* __restrict__ x,
                                                    unsigned short* __restrict__ At2) {
  __shared__ unsigned short ld[16 * 1028];   // [b_local][t_local*16+f], pitch 1028
  const int rb = blockIdx.x >> 4, tc = blockIdx.x & 15;
  const int tid = threadIdx.x;
  const int tl = tid >> 2;            // t-local 0..63
  const int f4 = (tid & 3) * 4;       // f quad
#pragma unroll
  for (int i = 0; i < 16; ++i) {
    const float* src = x + (((size_t)(rb * 16 + i) * T_) + tc * 64 + tl) * F_ + f4;
    float4 v = *(const float4*)src;
    uint2 pk;
    pk.x = (unsigned)f2bf(v.x) | ((unsigned)f2bf(v.y) << 16);
    pk.y = (unsigned)f2bf(v.z) | ((unsigned)f2bf(v.w) << 16);
    *(uint2*)&ld[i * 1028 + tl * 16 + f4] = pk;
  }
  __syncthreads();
  const int w = tid >> 6, l = tid & 63;
#pragma unroll
  for (int it = 0; it < 8; ++it) {
    const int c = it * 4 + w;          // 0..31 = (f, kcl)
    const int f = c >> 1, kcl = c & 1;
    unsigned short t16[8];
#pragma unroll
    for (int j = 0; j < 8; ++j)
      t16[j] = ld[(l & 15) * 1028 + (kcl * 32 + ((l >> 4) * 8) + j) * 16 + f];
    uint4 q;
    q.x = (unsigned)t16[0] | ((unsigned)t16[1] << 16);
    q.y = (unsigned)t16[2] | ((unsigned)t16[3] << 16);
    q.z = (unsigned)t16[4] | ((unsigned)t16[5] << 16);
    q.w = (unsigned)t16[6] | ((unsigned)t16[7] << 16);
    *(uint4*)(At2 + (((size_t)(f * 32 + tc * 2 + kcl) * 16 + rb) << 9) + l * 8) = q;
  }
}

// ---- pass 2: fused GEMM, gload_lds-staged weights, 1 barrier/tile ----
// acc[b,n] = sum_t x_bf16[b,t,f] * V[f,t,n]
// V[t] = c1*TW[t] + c2*RW[t] + 0.5*(TW[t-1] - RW[t-1]);  c1,c2 = (0.5,0.5) for
// t < T-1, (1,0) at t = T-1; prev-term dropped at t = 0.
// Grid 256 = 16f x 16 ntile (EBN=64), 1024 threads (16 waves).
// Weight staging via global_load_lds DMA (queue depth NOT VGPR-bound:
// 32 x 1KB in flight per CU vs ~8KB with reg staging — the diagnosed MLP
// limit). Double-buffered raw (linear, unpadded: DMA dest = base+lane*16;
// wave w stages rows 4w..4w+3, lane l -> row 4w+(l>>4), col (l&15)*4) and
// double-buffered vT -> ONE barrier per tile: it publishes vT[cur] for this
// tile's MFMA and drains raw[nxt] for the next tile's V-compute.
template <int TMPOUT>
__global__ __launch_bounds__(1024, 4) void gemm_kernel(const unsigned short* __restrict__ At2,
                                                       const float* __restrict__ TW,
                                                       const float* __restrict__ RW,
                                                       const float* __restrict__ tb,
                                                       const float* __restrict__ rb,
                                                       float* __restrict__ out,
                                                       unsigned short* __restrict__ tmp) {
  __shared__ float rawT[2][64 * 64];        // linear (DMA dest), V-reads stride-1 across n
  __shared__ float rawR[2][64 * 64];
  __shared__ unsigned short vT[2][64 * 72]; // V^T bf16, [n][t], pitch 72 shorts
  __shared__ float prevT[2][64], prevR[2][64];

  const int tid = threadIdx.x;
  // XCD chunk swizzle: grid 256, 8 XCDs -> 32 consecutive bids per XCD
  // (= 2 f-panels per XCD; At2 panels 2x512KB stay L2-resident).
  const int bid = (blockIdx.x & 7) * 32 + (blockIdx.x >> 3);
  const int f  = bid >> 4;
  const int n0 = (bid & 15) * 64;
  const int w = tid >> 6, l = tid & 63;     // wave 0..15, lane 0..63
  const int lrow = l & 15, lg = l >> 4;

  const float* TWf = TW + (size_t)f * (T_ * N_) + n0;
  const float* RWf = RW + (size_t)f * (T_ * N_) + n0;
  const unsigned short* Af2 = At2 + ((size_t)f * 32 * 16 * 512);

  // per-lane DMA source offset for this wave's 4-row slice (tile row base added per tile)
  const size_t gsrc = (size_t)(w * 4 + (l >> 4)) * N_ + (l & 15) * 4;

  f32x4 acc[4];                        // [nt], m-frag = w
#pragma unroll
  for (int nt = 0; nt < 4; ++nt)
    acc[nt] = (f32x4){0.f, 0.f, 0.f, 0.f};

  // prologue: DMA tile 0 weights + register A-frags
  gload16(TWf + gsrc, &rawT[0][w * 256]);
  gload16(RWf + gsrc, &rawR[0][w * 256]);
  bf16x8 afrag[2][2];                  // [buf][ks]
#pragma unroll
  for (int ks = 0; ks < 2; ++ks)
    afrag[0][ks] = *(const bf16x8*)(Af2 + (((size_t)(ks * 16 + w)) << 9) + l * 8);
  __syncthreads();   // raw[0] delivered

#pragma unroll
  for (int kt = 0; kt < 16; ++kt) {
    const int k0 = kt * 64;
    const int cur = kt & 1, nxt = cur ^ 1;
    // issue next tile's DMA + A-frag loads FIRST (in flight across V-compute)
    if (kt < 15) {
      gload16(TWf + (size_t)(k0 + 64) * N_ + gsrc, &rawT[nxt][w * 256]);
      gload16(RWf + (size_t)(k0 + 64) * N_ + gsrc, &rawR[nxt][w * 256]);
#pragma unroll
      for (int ks = 0; ks < 2; ++ks)
        afrag[nxt][ks] =
            *(const bf16x8*)(Af2 + (((size_t)(((kt + 1) * 2 + ks) * 16 + w)) << 9) + l * 8);
    }
    // ---- V-compute: wave w = t-strip w (4 rows), lane = n-col (stride-1) ----
    {
      float ptw, prw;
      if (w == 0) { ptw = prevT[cur ^ 1][l]; prw = prevR[cur ^ 1][l]; }
      else        { ptw = rawT[cur][(w * 4 - 1) * 64 + l]; prw = rawR[cur][(w * 4 - 1) * 64 + l]; }
      unsigned pk[2];
      unsigned lo32 = 0;
      float tw = 0.f, rw = 0.f;
#pragma unroll
      for (int i = 0; i < 4; ++i) {
        const int t = w * 4 + i, tg = k0 + t;
        tw = rawT[cur][t * 64 + l]; rw = rawR[cur][t * 64 + l];
        const float c1 = (tg < T_ - 1) ? 0.5f : 1.0f;
        const float c2 = (tg < T_ - 1) ? 0.5f : 0.0f;
        const float pterm = (tg >= 1) ? 0.5f * (ptw - prw) : 0.0f;
        const unsigned short us = f2bf(c1 * tw + c2 * rw + pterm);
        if ((i & 1) == 0) lo32 = us; else pk[i >> 1] = lo32 | ((unsigned)us << 16);
        ptw = tw; prw = rw;
      }
      uint2 q; q.x = pk[0]; q.y = pk[1];
      *(uint2*)&vT[cur][l * 72 + w * 4] = q;
      if (w == 15) { prevT[cur][l] = tw; prevR[cur][l] = rw; }
    }
    __syncthreads();   // publishes vT[cur]; drains raw[nxt] DMA
    // ---- MFMA: 2 ks x 4 nt (m-frag = w) ----
#pragma unroll
    for (int ks = 0; ks < 2; ++ks) {
#pragma unroll
      for (int nt = 0; nt < 4; ++nt) {
        bf16x8 bfrag = *(const bf16x8*)&vT[cur][(nt * 16 + lrow) * 72 + ks * 32 + lg * 8];
        acc[nt] = __builtin_amdgcn_mfma_f32_16x16x32_bf16(afrag[cur][ks], bfrag, acc[nt], 0, 0, 0);
      }
    }
  }

  // ---- epilogue: bias + store (wave w owns rows w*16..w*16+15) ----
#pragma unroll
  for (int nt = 0; nt < 4; ++nt) {
    const int n = n0 + nt * 16 + lrow;
    const float bsum = tb[f * N_ + n] + rb[f * N_ + n];
#pragma unroll
    for (int j = 0; j < 4; ++j) {
      const int brow = w * 16 + lg * 4 + j;
      const float v = acc[nt][j] + bsum;
      if (TMPOUT) {
        tmp[((size_t)f * B_ + brow) * N_ + n] = f2bf(v);          // coalesced 32B segments
      } else {
        out[((size_t)brow * N_ + n) * F_ + f] = v;                // scattered fallback
      }
    }
  }
}

// ---- pass 3: tmp[F][B][N] bf16 -> out[B][N][F] fp32, coalesced both sides ----
__global__ __launch_bounds__(256) void untile_kernel(const unsigned short* __restrict__ tmp,
                                                     float* __restrict__ out) {
  __shared__ unsigned short ld[16 * 1048];   // [f][n], padded pitch
  const int b = blockIdx.x, tid = threadIdx.x;
#pragma unroll
  for (int it = 0; it < 8; ++it) {
    const int idx = it * 256 + tid;
    const int f = idx >> 7, c = idx & 127;
    uint4 v = *(const uint4*)(tmp + ((size_t)f * B_ + b) * N_ + c * 8);
    *(uint4*)&ld[f * 1048 + c * 8] = v;
  }
  __syncthreads();
  float* ob = out + (size_t)b * (N_ * F_);
#pragma unroll
  for (int it = 0; it < 16; ++it) {
    const int g = it * 256 + tid;
    const int n = g >> 2, f0 = (g & 3) * 4;
    float4 o;
    o.x = bf2f(ld[(f0 + 0) * 1048 + n]);
    o.y = bf2f(ld[(f0 + 1) * 1048 + n]);
    o.z = bf2f(ld[(f0 + 2) * 1048 + n]);
    o.w = bf2f(ld[(f0 + 3) * 1048 + n]);
    *(float4*)(ob + n * F_ + f0) = o;
  }
}

extern "C" void kernel_launch(void* const* d_in, const int* in_sizes, int n_in,
                              void* d_out, int out_size, void* d_ws, size_t ws_size,
                              hipStream_t stream) {
  const float* x  = (const float*)d_in[0];
  const float* TW = (const float*)d_in[8];
  const float* tb = (const float*)d_in[9];
  const float* RW = (const float*)d_in[10];
  const float* rb = (const float*)d_in[11];
  float* out = (float*)d_out;

  unsigned short* At2 = (unsigned short*)d_ws;                // 8 MB
  const size_t atBytes  = (size_t)F_ * B_ * T_ * sizeof(unsigned short);
  const size_t tmpBytes = (size_t)F_ * B_ * N_ * sizeof(unsigned short);

  prep2_kernel<<<256, 256, 0, stream>>>(x, At2);
  if (ws_size >= atBytes + tmpBytes) {
    unsigned short* tmp = (unsigned short*)((char*)d_ws + atBytes);
    gemm_kernel<1><<<256, 1024, 0, stream>>>(At2, TW, RW, tb, rb, out, tmp);
    untile_kernel<<<256, 256, 0, stream>>>(tmp, out);
  } else {
    gemm_kernel<0><<<256, 1024, 0, stream>>>(At2, TW, RW, tb, rb, out, nullptr);
  }
}

// Round 17
// 41.938 us; speedup vs baseline: 1.1126x; 1.0594x over previous
//
#include <hip/hip_runtime.h>
#include <hip/hip_bf16.h>
#include <stdint.h>

#define B_  256
#define T_  1024
#define F_  16
#define N_  1024

typedef short bf16x8 __attribute__((ext_vector_type(8)));
typedef float f32x4  __attribute__((ext_vector_type(4)));

static __device__ __forceinline__ unsigned short f2bf(float x) {
  unsigned u = __builtin_bit_cast(unsigned, x);
  u += 0x7fffu + ((u >> 16) & 1u);
  return (unsigned short)(u >> 16);
}
static __device__ __forceinline__ float bf2f(unsigned short h) {
  unsigned u = ((unsigned)h) << 16;
  return __builtin_bit_cast(float, u);
}

// ---- pass 1: x[b][t][f] fp32 -> At2 fragment layout bf16 ----
// At2 element (f,b,k) at ((f*32+kc)*16+rb)*512 + lane*8 + j, where
// kc=k>>5, rb=b>>4, lane=((k>>3)&3)*16 + (b&15), j=k&7.
__global__ __launch_bounds__(256) void prep2_kernel(const float* __restrict__ x,
                                                    unsigned short* __restrict__ At2) {
  __shared__ unsigned short ld[16 * 1028];   // [b_local][t_local*16+f], pitch 1028
  const int rb = blockIdx.x >> 4, tc = blockIdx.x & 15;
  const int tid = threadIdx.x;
  const int tl = tid >> 2;            // t-local 0..63
  const int f4 = (tid & 3) * 4;       // f quad
#pragma unroll
  for (int i = 0; i < 16; ++i) {
    const float* src = x + (((size_t)(rb * 16 + i) * T_) + tc * 64 + tl) * F_ + f4;
    float4 v = *(const float4*)src;
    uint2 pk;
    pk.x = (unsigned)f2bf(v.x) | ((unsigned)f2bf(v.y) << 16);
    pk.y = (unsigned)f2bf(v.z) | ((unsigned)f2bf(v.w) << 16);
    *(uint2*)&ld[i * 1028 + tl * 16 + f4] = pk;
  }
  __syncthreads();
  const int w = tid >> 6, l = tid & 63;
#pragma unroll
  for (int it = 0; it < 8; ++it) {
    const int c = it * 4 + w;          // 0..31 = (f, kcl)
    const int f = c >> 1, kcl = c & 1;
    unsigned short t16[8];
#pragma unroll
    for (int j = 0; j < 8; ++j)
      t16[j] = ld[(l & 15) * 1028 + (kcl * 32 + ((l >> 4) * 8) + j) * 16 + f];
    uint4 q;
    q.x = (unsigned)t16[0] | ((unsigned)t16[1] << 16);
    q.y = (unsigned)t16[2] | ((unsigned)t16[3] << 16);
    q.z = (unsigned)t16[4] | ((unsigned)t16[5] << 16);
    q.w = (unsigned)t16[6] | ((unsigned)t16[7] << 16);
    *(uint4*)(At2 + (((size_t)(f * 32 + tc * 2 + kcl) * 16 + rb) << 9) + l * 8) = q;
  }
}

// ---- pass 2: fused GEMM, EBN=64, 1024-thread blocks (16 waves, m-frag = wave) ----
// acc[b,n] = sum_t x_bf16[b,t,f] * V[f,t,n]
// V[t] = c1*TW[t] + c2*RW[t] + 0.5*(TW[t-1] - RW[t-1]);  c1,c2 = (0.5,0.5) for
// t < T-1, (1,0) at t = T-1; prev-term dropped at t = 0.
// Per tile: each thread stages ONE float4 of each weight array (64x64 tile =
// 1024 threads x 16B); wave w loads 2 At2 chunks (1KB, coalesced) and runs
// 2ks x 4nt MFMA on its 16 rows. kt loop fully unrolled -> all frag indices
// static (no scratch; rule #20).
template <int TMPOUT>
__global__ __launch_bounds__(1024) void gemm_kernel(const unsigned short* __restrict__ At2,
                                                    const float* __restrict__ TW,
                                                    const float* __restrict__ RW,
                                                    const float* __restrict__ tb,
                                                    const float* __restrict__ rb,
                                                    float* __restrict__ out,
                                                    unsigned short* __restrict__ tmp) {
  __shared__ float rawT[64 * 64];           // [t][n] fp32 (V-reads are lane-across-n, stride-1)
  __shared__ float rawR[64 * 64];
  __shared__ unsigned short vT[64 * 72];    // V^T bf16, [n][t], pitch 72 shorts
  __shared__ float prevT[2][64], prevR[2][64];

  const int tid = threadIdx.x;
  // XCD chunk swizzle: grid 256, 8 XCDs -> 32 consecutive bids per XCD
  // (= 2 f-panels per XCD; At2 panels 2x512KB stay L2-resident).
  const int bid = (blockIdx.x & 7) * 32 + (blockIdx.x >> 3);
  const int f  = bid >> 4;
  const int n0 = (bid & 15) * 64;
  const int w = tid >> 6, l = tid & 63;     // wave 0..15, lane 0..63
  const int lrow = l & 15, lg = l >> 4;

  const float* TWf = TW + (size_t)f * (T_ * N_) + n0;
  const float* RWf = RW + (size_t)f * (T_ * N_) + n0;
  const unsigned short* Af2 = At2 + ((size_t)f * 32 * 16 * 512);

  // weight staging: one float4 per thread per array; rows 0..63 x cols 0..60
  const int wrow = tid >> 4;           // 0..63
  const int wc   = (tid & 15) * 4;     // 0..60 (floats)

  f32x4 acc[4];                        // [nt], m-frag = w
#pragma unroll
  for (int nt = 0; nt < 4; ++nt)
    acc[nt] = (f32x4){0.f, 0.f, 0.f, 0.f};

  // prologue: load tile 0 weights (regs) + A-frags
  float4 wtT = *(const float4*)(TWf + (size_t)wrow * N_ + wc);
  float4 wtR = *(const float4*)(RWf + (size_t)wrow * N_ + wc);
  bf16x8 afrag[2][2];                  // [buf][ks]
#pragma unroll
  for (int ks = 0; ks < 2; ++ks)
    afrag[0][ks] = *(const bf16x8*)(Af2 + (((size_t)(ks * 16 + w)) << 9) + l * 8);

#pragma unroll
  for (int kt = 0; kt < 16; ++kt) {
    const int k0 = kt * 64;
    __syncthreads();   // previous tile's vT / raw LDS fully consumed
    // commit staged weight regs -> LDS (vmcnt waits only on own loads)
    *(float4*)&rawT[wrow * 64 + wc] = wtT;
    *(float4*)&rawR[wrow * 64 + wc] = wtR;
    __syncthreads();   // raw ready
    // issue next tile's loads EARLY (drained at next iter's commit; covered
    // by V-compute + MFMA below)
    if (kt < 15) {
      wtT = *(const float4*)(TWf + (size_t)(k0 + 64 + wrow) * N_ + wc);
      wtR = *(const float4*)(RWf + (size_t)(k0 + 64 + wrow) * N_ + wc);
#pragma unroll
      for (int ks = 0; ks < 2; ++ks)
        afrag[(kt + 1) & 1][ks] =
            *(const bf16x8*)(Af2 + (((size_t)(((kt + 1) * 2 + ks) * 16 + w)) << 9) + l * 8);
    }
    // ---- V-compute: wave w = t-strip w (4 rows), lane = n-col (stride-1) ----
    {
      float ptw, prw;
      if (w == 0) { ptw = prevT[(kt & 1) ^ 1][l]; prw = prevR[(kt & 1) ^ 1][l]; }
      else        { ptw = rawT[(w * 4 - 1) * 64 + l]; prw = rawR[(w * 4 - 1) * 64 + l]; }
      unsigned pk[2];
      unsigned lo32 = 0;
      float tw = 0.f, rw = 0.f;
#pragma unroll
      for (int i = 0; i < 4; ++i) {
        const int t = w * 4 + i, tg = k0 + t;
        tw = rawT[t * 64 + l]; rw = rawR[t * 64 + l];
        const float c1 = (tg < T_ - 1) ? 0.5f : 1.0f;
        const float c2 = (tg < T_ - 1) ? 0.5f : 0.0f;
        const float pterm = (tg >= 1) ? 0.5f * (ptw - prw) : 0.0f;
        const unsigned short us = f2bf(c1 * tw + c2 * rw + pterm);
        if ((i & 1) == 0) lo32 = us; else pk[i >> 1] = lo32 | ((unsigned)us << 16);
        ptw = tw; prw = rw;
      }
      uint2 q; q.x = pk[0]; q.y = pk[1];
      *(uint2*)&vT[l * 72 + w * 4] = q;
      if (w == 15) { prevT[kt & 1][l] = tw; prevR[kt & 1][l] = rw; }
    }
    __syncthreads();   // vT ready
    // ---- MFMA: 2 ks x 4 nt (m-frag = w) ----
#pragma unroll
    for (int ks = 0; ks < 2; ++ks) {
#pragma unroll
      for (int nt = 0; nt < 4; ++nt) {
        bf16x8 bfrag = *(const bf16x8*)&vT[(nt * 16 + lrow) * 72 + ks * 32 + lg * 8];
        acc[nt] = __builtin_amdgcn_mfma_f32_16x16x32_bf16(afrag[kt & 1][ks], bfrag, acc[nt], 0, 0, 0);
      }
    }
  }

  // ---- epilogue: bias + store (wave w owns rows w*16..w*16+15) ----
#pragma unroll
  for (int nt = 0; nt < 4; ++nt) {
    const int n = n0 + nt * 16 + lrow;
    const float bsum = tb[f * N_ + n] + rb[f * N_ + n];
#pragma unroll
    for (int j = 0; j < 4; ++j) {
      const int brow = w * 16 + lg * 4 + j;
      const float v = acc[nt][j] + bsum;
      if (TMPOUT) {
        tmp[((size_t)f * B_ + brow) * N_ + n] = f2bf(v);          // coalesced 32B segments
      } else {
        out[((size_t)brow * N_ + n) * F_ + f] = v;                // scattered fallback
      }
    }
  }
}

// ---- pass 3: tmp[F][B][N] bf16 -> out[B][N][F] fp32, coalesced both sides ----
__global__ __launch_bounds__(256) void untile_kernel(const unsigned short* __restrict__ tmp,
                                                     float* __restrict__ out) {
  __shared__ unsigned short ld[16 * 1048];   // [f][n], padded pitch
  const int b = blockIdx.x, tid = threadIdx.x;
#pragma unroll
  for (int it = 0; it < 8; ++it) {
    const int idx = it * 256 + tid;
    const int f = idx >> 7, c = idx & 127;
    uint4 v = *(const uint4*)(tmp + ((size_t)f * B_ + b) * N_ + c * 8);
    *(uint4*)&ld[f * 1048 + c * 8] = v;
  }
  __syncthreads();
  float* ob = out + (size_t)b * (N_ * F_);
#pragma unroll
  for (int it = 0; it < 16; ++it) {
    const int g = it * 256 + tid;
    const int n = g >> 2, f0 = (g & 3) * 4;
    float4 o;
    o.x = bf2f(ld[(f0 + 0) * 1048 + n]);
    o.y = bf2f(ld[(f0 + 1) * 1048 + n]);
    o.z = bf2f(ld[(f0 + 2) * 1048 + n]);
    o.w = bf2f(ld[(f0 + 3) * 1048 + n]);
    *(float4*)(ob + n * F_ + f0) = o;
  }
}

extern "C" void kernel_launch(void* const* d_in, const int* in_sizes, int n_in,
                              void* d_out, int out_size, void* d_ws, size_t ws_size,
                              hipStream_t stream) {
  const float* x  = (const float*)d_in[0];
  const float* TW = (const float*)d_in[8];
  const float* tb = (const float*)d_in[9];
  const float* RW = (const float*)d_in[10];
  const float* rb = (const float*)d_in[11];
  float* out = (float*)d_out;

  unsigned short* At2 = (unsigned short*)d_ws;                // 8 MB
  const size_t atBytes  = (size_t)F_ * B_ * T_ * sizeof(unsigned short);
  const size_t tmpBytes = (size_t)F_ * B_ * N_ * sizeof(unsigned short);

  prep2_kernel<<<256, 256, 0, stream>>>(x, At2);
  if (ws_size >= atBytes + tmpBytes) {
    unsigned short* tmp = (unsigned short*)((char*)d_ws + atBytes);
    gemm_kernel<1><<<256, 1024, 0, stream>>>(At2, TW, RW, tb, rb, out, tmp);
    untile_kernel<<<256, 256, 0, stream>>>(tmp, out);
  } else {
    gemm_kernel<0><<<256, 1024, 0, stream>>>(At2, TW, RW, tb, rb, out, nullptr);
  }
}